// Round 1
// baseline (877.271 us; speedup 1.0000x reference)
//
#include <hip/hip_runtime.h>

#define BN 2
#define T_DIM 2048
#define D_DIM 1024
#define H_N 16
#define DH_N 64
#define WIN 256
#define NROWS (BN * T_DIM)   // 4096

// ---------------------------------------------------------------------------
// Kernel 1: qkv = x @ w_qkv + b_qkv ; scatter into q/k/v [B,H,T,DH], q*=0.125
// X [4096][1024] row-major, W [1024][3072] row-major.
// 64x64 tile, BK=16, 256 threads, 4x4 per thread.
// ---------------------------------------------------------------------------
__global__ __launch_bounds__(256) void qkv_gemm(
    const float* __restrict__ X, const float* __restrict__ W,
    const float* __restrict__ bias, float* __restrict__ qo,
    float* __restrict__ ko, float* __restrict__ vo) {
  __shared__ float As[16][64];  // As[kk][(row + 4*kk) & 63]
  __shared__ float Bs[16][64];  // Bs[kk][col]
  const int tid = threadIdx.x;
  const int r0 = blockIdx.y * 64;
  const int c0 = blockIdx.x * 64;
  const int tx = tid & 15, ty = tid >> 4;

  float acc[4][4];
#pragma unroll
  for (int i = 0; i < 4; ++i)
#pragma unroll
    for (int j = 0; j < 4; ++j) acc[i][j] = 0.f;

  for (int k0 = 0; k0 < D_DIM; k0 += 16) {
    __syncthreads();
#pragma unroll
    for (int i = 0; i < 4; ++i) {
      int idx = i * 256 + tid;
      int kk = idx & 15, row = idx >> 4;
      As[kk][(row + 4 * kk) & 63] = X[(r0 + row) * D_DIM + k0 + kk];
      int kk2 = idx >> 6, col = idx & 63;
      Bs[kk2][col] = W[(k0 + kk2) * (3 * D_DIM) + c0 + col];
    }
    __syncthreads();
#pragma unroll
    for (int kk = 0; kk < 16; ++kk) {
      float a[4], b[4];
#pragma unroll
      for (int i = 0; i < 4; ++i) a[i] = As[kk][((ty * 4 + i) + 4 * kk) & 63];
#pragma unroll
      for (int j = 0; j < 4; ++j) b[j] = Bs[kk][tx * 4 + j];
#pragma unroll
      for (int i = 0; i < 4; ++i)
#pragma unroll
        for (int j = 0; j < 4; ++j) acc[i][j] += a[i] * b[j];
    }
  }

  // epilogue: block-uniform which/head (c0 is 64-aligned, 1024 % 64 == 0)
  const int which = c0 >> 10;       // 0=q,1=k,2=v
  const int dcol = c0 & 1023;
  const int h = dcol >> 6;
  float* dst = (which == 0) ? qo : ((which == 1) ? ko : vo);
  const float mul = (which == 0) ? 0.125f : 1.0f;  // SCALE = 64^-0.5

#pragma unroll
  for (int i = 0; i < 4; ++i) {
    int r = r0 + ty * 4 + i;
    int b_ = r >> 11, t = r & 2047;
    size_t base = ((size_t)(b_ * H_N + h) * T_DIM + t) * DH_N;
#pragma unroll
    for (int j = 0; j < 4; ++j) {
      int dh = tx * 4 + j;
      dst[base + dh] = (acc[i][j] + bias[c0 + dh]) * mul;
    }
  }
}

// ---------------------------------------------------------------------------
// Kernel 2: windowed causal flash attention, f32.
// block = (b,h, 64 q-rows); 256 threads = 64 rows x 4 subthreads.
// LDS swizzle (col+row)&63 everywhere -> <=2-way conflicts.
// ---------------------------------------------------------------------------
__global__ __launch_bounds__(256) void attn_kernel(
    const float* __restrict__ qg, const float* __restrict__ kg,
    const float* __restrict__ vg, float* __restrict__ ctx) {
  __shared__ float Qs[64][64];
  __shared__ float Ks[64][64];  // reused to hold P after scores consumed
  __shared__ float Vs[64][64];

  const int tid = threadIdx.x;
  const int qt = blockIdx.x & 31;  // 2048/64 = 32 q-tiles
  const int bh = blockIdx.x >> 5;  // b*16 + h
  const int q0 = qt * 64;
  const float* qp = qg + (size_t)bh * T_DIM * DH_N + (size_t)q0 * DH_N;
  const float* kp = kg + (size_t)bh * T_DIM * DH_N;
  const float* vp = vg + (size_t)bh * T_DIM * DH_N;

#pragma unroll
  for (int i = 0; i < 16; ++i) {
    int idx = i * 256 + tid;
    int row = idx >> 6, d = idx & 63;
    Qs[row][(d + row) & 63] = qp[idx];
  }

  const int r = tid >> 2, sub = tid & 3;
  const int ig = q0 + r;  // global query index
  float m = -1e30f, l = 0.f, o[16];
#pragma unroll
  for (int i = 0; i < 16; ++i) o[i] = 0.f;

  for (int kt = q0 - WIN; kt <= q0; kt += 64) {
    if (kt < 0) continue;
    __syncthreads();  // previous tile's P/V reads done
#pragma unroll
    for (int i = 0; i < 16; ++i) {
      int idx = i * 256 + tid;
      int row = idx >> 6, d = idx & 63;
      Ks[row][(d + row) & 63] = kp[(size_t)kt * DH_N + idx];
      Vs[row][(d + row) & 63] = vp[(size_t)kt * DH_N + idx];
    }
    __syncthreads();

    // scores for keys kt + sub*16 + mm  (q already carries SCALE)
    float s[16];
#pragma unroll
    for (int mm = 0; mm < 16; ++mm) s[mm] = 0.f;
    for (int d = 0; d < 64; ++d) {
      float qv = Qs[r][(d + r) & 63];
#pragma unroll
      for (int mm = 0; mm < 16; ++mm) {
        int key = sub * 16 + mm;
        s[mm] += qv * Ks[key][(d + key) & 63];
      }
    }
    float tm = -1e30f;
#pragma unroll
    for (int mm = 0; mm < 16; ++mm) {
      int j = kt + sub * 16 + mm;
      if (j > ig || j < ig - WIN) s[mm] = -1e30f;
      tm = fmaxf(tm, s[mm]);
    }
    tm = fmaxf(tm, __shfl_xor(tm, 1, 4));
    tm = fmaxf(tm, __shfl_xor(tm, 2, 4));
    float mn = fmaxf(m, tm);
    float sc = __expf(m - mn);
    float p[16];
    float ls = 0.f;
#pragma unroll
    for (int mm = 0; mm < 16; ++mm) {
      p[mm] = __expf(s[mm] - mn);
      ls += p[mm];
    }
    ls += __shfl_xor(ls, 1, 4);
    ls += __shfl_xor(ls, 2, 4);
    l = l * sc + ls;
    m = mn;
#pragma unroll
    for (int i = 0; i < 16; ++i) o[i] *= sc;

    __syncthreads();  // done reading Ks as scores source
    // write P transposed into Ks buffer: P[key][row]
#pragma unroll
    for (int mm = 0; mm < 16; ++mm) {
      int key = sub * 16 + mm;
      Ks[key][(r + key) & 63] = p[mm];
    }
    __syncthreads();

    for (int key = 0; key < 64; ++key) {
      float pv = Ks[key][(r + key) & 63];
#pragma unroll
      for (int dd = 0; dd < 16; ++dd) {
        int d = sub * 16 + dd;
        o[dd] += pv * Vs[key][(d + key) & 63];
      }
    }
  }

  float inv = 1.f / l;
  const int b_ = bh >> 4, h = bh & 15;
  float* op = ctx + ((size_t)b_ * T_DIM + (q0 + r)) * D_DIM + h * DH_N + sub * 16;
#pragma unroll
  for (int dd = 0; dd < 16; ++dd) op[dd] = o[dd] * inv;
}

// ---------------------------------------------------------------------------
// Kernel 3: out = ctx @ w_out + b_out.  ctx [4096][1024], W [1024][1024].
// ---------------------------------------------------------------------------
__global__ __launch_bounds__(256) void out_gemm(
    const float* __restrict__ X, const float* __restrict__ W,
    const float* __restrict__ bias, float* __restrict__ out) {
  __shared__ float As[16][64];
  __shared__ float Bs[16][64];
  const int tid = threadIdx.x;
  const int r0 = blockIdx.y * 64;
  const int c0 = blockIdx.x * 64;
  const int tx = tid & 15, ty = tid >> 4;

  float acc[4][4];
#pragma unroll
  for (int i = 0; i < 4; ++i)
#pragma unroll
    for (int j = 0; j < 4; ++j) acc[i][j] = 0.f;

  for (int k0 = 0; k0 < D_DIM; k0 += 16) {
    __syncthreads();
#pragma unroll
    for (int i = 0; i < 4; ++i) {
      int idx = i * 256 + tid;
      int kk = idx & 15, row = idx >> 4;
      As[kk][(row + 4 * kk) & 63] = X[(r0 + row) * D_DIM + k0 + kk];
      int kk2 = idx >> 6, col = idx & 63;
      Bs[kk2][col] = W[(k0 + kk2) * D_DIM + c0 + col];
    }
    __syncthreads();
#pragma unroll
    for (int kk = 0; kk < 16; ++kk) {
      float a[4], b[4];
#pragma unroll
      for (int i = 0; i < 4; ++i) a[i] = As[kk][((ty * 4 + i) + 4 * kk) & 63];
#pragma unroll
      for (int j = 0; j < 4; ++j) b[j] = Bs[kk][tx * 4 + j];
#pragma unroll
      for (int i = 0; i < 4; ++i)
#pragma unroll
        for (int j = 0; j < 4; ++j) acc[i][j] += a[i] * b[j];
    }
  }

#pragma unroll
  for (int i = 0; i < 4; ++i) {
    int rr = r0 + ty * 4 + i;
#pragma unroll
    for (int j = 0; j < 4; ++j) {
      int c = c0 + tx * 4 + j;
      out[(size_t)rr * D_DIM + c] = acc[i][j] + bias[c];
    }
  }
}

// ---------------------------------------------------------------------------
extern "C" void kernel_launch(void* const* d_in, const int* in_sizes, int n_in,
                              void* d_out, int out_size, void* d_ws,
                              size_t ws_size, hipStream_t stream) {
  const float* x = (const float*)d_in[0];
  const float* w_qkv = (const float*)d_in[1];
  const float* b_qkv = (const float*)d_in[2];
  const float* w_out = (const float*)d_in[3];
  const float* b_out = (const float*)d_in[4];
  float* out = (float*)d_out;

  const size_t per = (size_t)BN * H_N * T_DIM * DH_N;  // 4,194,304 floats
  float* q = (float*)d_ws;
  float* k = q + per;
  float* v = k + per;
  float* ctx = v + per;  // [B,T,D] f32; total ws use = 64 MB

  qkv_gemm<<<dim3(3 * D_DIM / 64, NROWS / 64), dim3(256), 0, stream>>>(
      x, w_qkv, b_qkv, q, k, v);
  attn_kernel<<<dim3(BN * H_N * (T_DIM / 64)), dim3(256), 0, stream>>>(
      q, k, v, ctx);
  out_gemm<<<dim3(D_DIM / 64, NROWS / 64), dim3(256), 0, stream>>>(
      ctx, w_out, b_out, out);
}

// Round 2
// 414.642 us; speedup vs baseline: 2.1157x; 2.1157x over previous
//
#include <hip/hip_runtime.h>

#define BN 2
#define T_DIM 2048
#define D_DIM 1024
#define H_N 16
#define DH_N 64
#define WIN 256
#define NROWS (BN * T_DIM)   // 4096
#define KDIM 1024            // inner dim for both GEMMs (A and Bt stride)

typedef __attribute__((ext_vector_type(8))) short bf16x8;
typedef __attribute__((ext_vector_type(4))) float f32x4;
typedef __attribute__((ext_vector_type(8))) unsigned short ushort8;

static __device__ __forceinline__ unsigned short f2bf(float f) {
  unsigned int u = __float_as_uint(f);
  unsigned int r = (u + 0x7FFFu + ((u >> 16) & 1u)) >> 16;  // RNE
  return (unsigned short)r;
}

static __device__ __forceinline__ void gl_lds16(const void* g, void* l) {
  __builtin_amdgcn_global_load_lds(
      (const __attribute__((address_space(1))) unsigned int*)g,
      (__attribute__((address_space(3))) unsigned int*)l, 16, 0, 0);
}

// ---------------------------------------------------------------------------
// f32 -> bf16 elementwise (8 elems/thread)
// ---------------------------------------------------------------------------
__global__ __launch_bounds__(256) void convert_bf(const float* __restrict__ src,
                                                  unsigned short* __restrict__ dst) {
  int i = (blockIdx.x * 256 + threadIdx.x) * 8;
  float4 a = *(const float4*)(src + i);
  float4 b = *(const float4*)(src + i + 4);
  ushort8 o;
  o[0] = f2bf(a.x); o[1] = f2bf(a.y); o[2] = f2bf(a.z); o[3] = f2bf(a.w);
  o[4] = f2bf(b.x); o[5] = f2bf(b.y); o[6] = f2bf(b.z); o[7] = f2bf(b.w);
  *(ushort8*)(dst + i) = o;
}

// ---------------------------------------------------------------------------
// f32 [R][C] -> bf16 [C][R] tiled transpose (64x64 tiles)
// ---------------------------------------------------------------------------
__global__ __launch_bounds__(256) void convert_t(const float* __restrict__ src,
                                                 unsigned short* __restrict__ dst,
                                                 int R, int C) {
  __shared__ float tile[64][65];
  const int t = threadIdx.x;
  const int bc = blockIdx.x * 64, br = blockIdx.y * 64;
#pragma unroll
  for (int i = 0; i < 16; ++i) {
    int idx = i * 256 + t;
    int r = idx >> 6, c = idx & 63;
    tile[r][c] = src[(size_t)(br + r) * C + bc + c];
  }
  __syncthreads();
#pragma unroll
  for (int i = 0; i < 16; ++i) {
    int idx = i * 256 + t;
    int r = idx >> 6, c = idx & 63;  // output row r = orig col, output col c = orig row
    dst[(size_t)(bc + r) * R + br + c] = f2bf(tile[c][r]);
  }
}

// ---------------------------------------------------------------------------
// bf16 MFMA GEMM, m97 structure: 128x128 tile, BK=32, 4 waves (2x2),
// global_load_lds width=16, 16x16x32 MFMA, f32 accum.
// A [M][1024] bf16 row-major; Bt [N][1024] bf16 row-major (B transposed).
// EPI 0: C = A@B + bias -> out [M][1024] f32
// EPI 1: qkv scatter -> q/k/v [B,H,T,64] f32, q scaled by 0.125
// ---------------------------------------------------------------------------
template <int EPI>
__global__ __launch_bounds__(256) void mfma_gemm(
    const unsigned short* __restrict__ A, const unsigned short* __restrict__ Bt,
    const float* __restrict__ bias, float* __restrict__ qo,
    float* __restrict__ ko, float* __restrict__ vo) {
  __shared__ unsigned short As[128 * 32];
  __shared__ unsigned short Bs[128 * 32];
  const int tid = threadIdx.x;
  const int w = tid >> 6, l = tid & 63;
  const int wr = w >> 1, wc = w & 1;
  const int r0 = blockIdx.y * 128, c0 = blockIdx.x * 128;

  f32x4 acc[4][4];
#pragma unroll
  for (int i = 0; i < 4; ++i)
#pragma unroll
    for (int j = 0; j < 4; ++j) acc[i][j] = (f32x4){0.f, 0.f, 0.f, 0.f};

  const unsigned short* Ag = A + (size_t)r0 * KDIM;
  const unsigned short* Bg = Bt + (size_t)c0 * KDIM;
  const int srow = l >> 2;            // row within 16-row stage chunk
  const int skoff = (l & 3) * 8;      // k element offset within BK

  for (int k0 = 0; k0 < KDIM; k0 += 32) {
#pragma unroll
    for (int i = 0; i < 2; ++i) {
      int chunk = i * 4 + w;          // 0..7, 16 rows each
      int m = chunk * 16 + srow;
      gl_lds16(Ag + (size_t)m * KDIM + k0 + skoff, (char*)As + chunk * 1024);
      gl_lds16(Bg + (size_t)m * KDIM + k0 + skoff, (char*)Bs + chunk * 1024);
    }
    __syncthreads();  // drains vmcnt(0): staged data visible

    bf16x8 a[4], b[4];
#pragma unroll
    for (int mi = 0; mi < 4; ++mi)
      a[mi] = *(const bf16x8*)((const char*)As +
                               (wr * 64 + mi * 16 + (l & 15)) * 64 + (l >> 4) * 16);
#pragma unroll
    for (int ni = 0; ni < 4; ++ni)
      b[ni] = *(const bf16x8*)((const char*)Bs +
                               (wc * 64 + ni * 16 + (l & 15)) * 64 + (l >> 4) * 16);
#pragma unroll
    for (int mi = 0; mi < 4; ++mi)
#pragma unroll
      for (int ni = 0; ni < 4; ++ni)
        acc[mi][ni] = __builtin_amdgcn_mfma_f32_16x16x32_bf16(a[mi], b[ni],
                                                              acc[mi][ni], 0, 0, 0);
    __syncthreads();  // before next stage overwrites
  }

  // epilogue: C row = (lane>>4)*4 + reg, col = lane&15 (guide §3, m89-verified)
#pragma unroll
  for (int mi = 0; mi < 4; ++mi) {
#pragma unroll
    for (int ni = 0; ni < 4; ++ni) {
      int row = r0 + wr * 64 + mi * 16 + (l >> 4) * 4;
      int col = c0 + wc * 64 + ni * 16 + (l & 15);
      float bv = bias[col];
      if (EPI == 0) {
#pragma unroll
        for (int j = 0; j < 4; ++j)
          qo[(size_t)(row + j) * D_DIM + col] = acc[mi][ni][j] + bv;
      } else {
        int which = col >> 10;          // 0=q,1=k,2=v
        int h = (col >> 6) & 15;
        int dh = col & 63;
        float mul = (which == 0) ? 0.125f : 1.0f;
        float* dst = (which == 0) ? qo : ((which == 1) ? ko : vo);
#pragma unroll
        for (int j = 0; j < 4; ++j) {
          int r = row + j;
          int b_ = r >> 11, t = r & 2047;
          dst[((size_t)(b_ * H_N + h) * T_DIM + t) * DH_N + dh] =
              (acc[mi][ni][j] + bv) * mul;
        }
      }
    }
  }
}

// ---------------------------------------------------------------------------
// Kernel 2: windowed causal flash attention, f32 (unchanged math);
// now writes ctx as bf16 for the out-proj MFMA.
// ---------------------------------------------------------------------------
__global__ __launch_bounds__(256) void attn_kernel(
    const float* __restrict__ qg, const float* __restrict__ kg,
    const float* __restrict__ vg, unsigned short* __restrict__ ctx) {
  __shared__ float Qs[64][64];
  __shared__ float Ks[64][64];
  __shared__ float Vs[64][64];

  const int tid = threadIdx.x;
  const int qt = blockIdx.x & 31;
  const int bh = blockIdx.x >> 5;
  const int q0 = qt * 64;
  const float* qp = qg + (size_t)bh * T_DIM * DH_N + (size_t)q0 * DH_N;
  const float* kp = kg + (size_t)bh * T_DIM * DH_N;
  const float* vp = vg + (size_t)bh * T_DIM * DH_N;

#pragma unroll
  for (int i = 0; i < 16; ++i) {
    int idx = i * 256 + tid;
    int row = idx >> 6, d = idx & 63;
    Qs[row][(d + row) & 63] = qp[idx];
  }

  const int r = tid >> 2, sub = tid & 3;
  const int ig = q0 + r;
  float m = -1e30f, lsum = 0.f, o[16];
#pragma unroll
  for (int i = 0; i < 16; ++i) o[i] = 0.f;

  for (int kt = q0 - WIN; kt <= q0; kt += 64) {
    if (kt < 0) continue;
    __syncthreads();
#pragma unroll
    for (int i = 0; i < 16; ++i) {
      int idx = i * 256 + tid;
      int row = idx >> 6, d = idx & 63;
      Ks[row][(d + row) & 63] = kp[(size_t)kt * DH_N + idx];
      Vs[row][(d + row) & 63] = vp[(size_t)kt * DH_N + idx];
    }
    __syncthreads();

    float s[16];
#pragma unroll
    for (int mm = 0; mm < 16; ++mm) s[mm] = 0.f;
    for (int d = 0; d < 64; ++d) {
      float qv = Qs[r][(d + r) & 63];
#pragma unroll
      for (int mm = 0; mm < 16; ++mm) {
        int key = sub * 16 + mm;
        s[mm] += qv * Ks[key][(d + key) & 63];
      }
    }
    float tm = -1e30f;
#pragma unroll
    for (int mm = 0; mm < 16; ++mm) {
      int j = kt + sub * 16 + mm;
      if (j > ig || j < ig - WIN) s[mm] = -1e30f;
      tm = fmaxf(tm, s[mm]);
    }
    tm = fmaxf(tm, __shfl_xor(tm, 1, 4));
    tm = fmaxf(tm, __shfl_xor(tm, 2, 4));
    float mn = fmaxf(m, tm);
    float sc = __expf(m - mn);
    float p[16];
    float ls = 0.f;
#pragma unroll
    for (int mm = 0; mm < 16; ++mm) {
      p[mm] = __expf(s[mm] - mn);
      ls += p[mm];
    }
    ls += __shfl_xor(ls, 1, 4);
    ls += __shfl_xor(ls, 2, 4);
    lsum = lsum * sc + ls;
    m = mn;
#pragma unroll
    for (int i = 0; i < 16; ++i) o[i] *= sc;

    __syncthreads();
#pragma unroll
    for (int mm = 0; mm < 16; ++mm) {
      int key = sub * 16 + mm;
      Ks[key][(r + key) & 63] = p[mm];
    }
    __syncthreads();

    for (int key = 0; key < 64; ++key) {
      float pv = Ks[key][(r + key) & 63];
#pragma unroll
      for (int dd = 0; dd < 16; ++dd) {
        int d = sub * 16 + dd;
        o[dd] += pv * Vs[key][(d + key) & 63];
      }
    }
  }

  float inv = 1.f / lsum;
  const int b_ = bh >> 4, h = bh & 15;
  unsigned short* op =
      ctx + ((size_t)b_ * T_DIM + (q0 + r)) * D_DIM + h * DH_N + sub * 16;
  ushort8 o0, o1;
#pragma unroll
  for (int dd = 0; dd < 8; ++dd) o0[dd] = f2bf(o[dd] * inv);
#pragma unroll
  for (int dd = 0; dd < 8; ++dd) o1[dd] = f2bf(o[8 + dd] * inv);
  *(ushort8*)op = o0;
  *(ushort8*)(op + 8) = o1;
}

// ---------------------------------------------------------------------------
extern "C" void kernel_launch(void* const* d_in, const int* in_sizes, int n_in,
                              void* d_out, int out_size, void* d_ws,
                              size_t ws_size, hipStream_t stream) {
  const float* x = (const float*)d_in[0];
  const float* w_qkv = (const float*)d_in[1];
  const float* b_qkv = (const float*)d_in[2];
  const float* w_out = (const float*)d_in[3];
  const float* b_out = (const float*)d_in[4];
  float* out = (float*)d_out;

  const size_t per = (size_t)BN * H_N * T_DIM * DH_N;  // 4,194,304
  float* q = (float*)d_ws;
  float* k = q + per;
  float* v = k + per;
  unsigned short* xbf = (unsigned short*)(v + per);        // [4096][1024]
  unsigned short* wqkvt = xbf + (size_t)NROWS * D_DIM;     // [3072][1024]
  unsigned short* woutt = wqkvt + (size_t)3 * D_DIM * D_DIM;  // [1024][1024]
  unsigned short* ctxbf = woutt + (size_t)D_DIM * D_DIM;   // [4096][1024]

  // conversions
  convert_bf<<<dim3(NROWS * D_DIM / (256 * 8)), dim3(256), 0, stream>>>(x, xbf);
  convert_t<<<dim3(3 * D_DIM / 64, D_DIM / 64), dim3(256), 0, stream>>>(
      w_qkv, wqkvt, D_DIM, 3 * D_DIM);
  convert_t<<<dim3(D_DIM / 64, D_DIM / 64), dim3(256), 0, stream>>>(
      w_out, woutt, D_DIM, D_DIM);

  // qkv = x @ w_qkv + b (scatter to q/k/v, q*=0.125)
  mfma_gemm<1><<<dim3(3 * D_DIM / 128, NROWS / 128), dim3(256), 0, stream>>>(
      xbf, wqkvt, b_qkv, q, k, v);

  attn_kernel<<<dim3(BN * H_N * (T_DIM / 64)), dim3(256), 0, stream>>>(
      q, k, v, ctxbf);

  // out = ctx @ w_out + b
  mfma_gemm<0><<<dim3(D_DIM / 128, NROWS / 128), dim3(256), 0, stream>>>(
      ctxbf, woutt, b_out, out, nullptr, nullptr);
}

// Round 3
// 107.964 us; speedup vs baseline: 8.1256x; 3.8406x over previous
//
#include <hip/hip_runtime.h>

#define BN 2
#define T_DIM 2048
#define D_DIM 1024
#define H_N 16
#define DH_N 64
#define WIN 256
#define NROWS (BN * T_DIM)   // 4096
#define KDIM 1024            // inner dim for both GEMMs (A and Bt stride)

typedef __attribute__((ext_vector_type(8))) short bf16x8;
typedef __attribute__((ext_vector_type(4))) float f32x4;
typedef __attribute__((ext_vector_type(8))) unsigned short ushort8;
typedef __attribute__((ext_vector_type(4))) unsigned short u16x4;

static __device__ __forceinline__ unsigned short f2bf(float f) {
  unsigned int u = __float_as_uint(f);
  unsigned int r = (u + 0x7FFFu + ((u >> 16) & 1u)) >> 16;  // RNE
  return (unsigned short)r;
}

static __device__ __forceinline__ void gl_lds16(const void* g, void* l) {
  __builtin_amdgcn_global_load_lds(
      (const __attribute__((address_space(1))) unsigned int*)g,
      (__attribute__((address_space(3))) unsigned int*)l, 16, 0, 0);
}

// ---------------------------------------------------------------------------
// f32 -> bf16 elementwise (8 elems/thread)
// ---------------------------------------------------------------------------
__global__ __launch_bounds__(256) void convert_bf(const float* __restrict__ src,
                                                  unsigned short* __restrict__ dst) {
  int i = (blockIdx.x * 256 + threadIdx.x) * 8;
  float4 a = *(const float4*)(src + i);
  float4 b = *(const float4*)(src + i + 4);
  ushort8 o;
  o[0] = f2bf(a.x); o[1] = f2bf(a.y); o[2] = f2bf(a.z); o[3] = f2bf(a.w);
  o[4] = f2bf(b.x); o[5] = f2bf(b.y); o[6] = f2bf(b.z); o[7] = f2bf(b.w);
  *(ushort8*)(dst + i) = o;
}

// ---------------------------------------------------------------------------
// f32 [R][C] -> bf16 [C][R] tiled transpose (64x64 tiles)
// ---------------------------------------------------------------------------
__global__ __launch_bounds__(256) void convert_t(const float* __restrict__ src,
                                                 unsigned short* __restrict__ dst,
                                                 int R, int C) {
  __shared__ float tile[64][65];
  const int t = threadIdx.x;
  const int bc = blockIdx.x * 64, br = blockIdx.y * 64;
#pragma unroll
  for (int i = 0; i < 16; ++i) {
    int idx = i * 256 + t;
    int r = idx >> 6, c = idx & 63;
    tile[r][c] = src[(size_t)(br + r) * C + bc + c];
  }
  __syncthreads();
#pragma unroll
  for (int i = 0; i < 16; ++i) {
    int idx = i * 256 + t;
    int r = idx >> 6, c = idx & 63;
    dst[(size_t)(bc + r) * R + br + c] = f2bf(tile[c][r]);
  }
}

// ---------------------------------------------------------------------------
// bf16 MFMA GEMM (m97 structure): 128x128 tile, BK=32, 4 waves (2x2).
// EPI 0: C = A@B + bias -> float out [M][1024]
// EPI 1: qkv -> q,k bf16 [B,H,T,64] (q*0.125), v bf16 TRANSPOSED [B,H,64,T]
// ---------------------------------------------------------------------------
template <int EPI>
__global__ __launch_bounds__(256) void mfma_gemm(
    const unsigned short* __restrict__ A, const unsigned short* __restrict__ Bt,
    const float* __restrict__ bias, float* __restrict__ fo,
    unsigned short* __restrict__ qo, unsigned short* __restrict__ ko,
    unsigned short* __restrict__ vto) {
  __shared__ unsigned short As[128 * 32];
  __shared__ unsigned short Bs[128 * 32];
  const int tid = threadIdx.x;
  const int w = tid >> 6, l = tid & 63;
  const int wr = w >> 1, wc = w & 1;
  const int r0 = blockIdx.y * 128, c0 = blockIdx.x * 128;

  f32x4 acc[4][4];
#pragma unroll
  for (int i = 0; i < 4; ++i)
#pragma unroll
    for (int j = 0; j < 4; ++j) acc[i][j] = (f32x4){0.f, 0.f, 0.f, 0.f};

  const unsigned short* Ag = A + (size_t)r0 * KDIM;
  const unsigned short* Bg = Bt + (size_t)c0 * KDIM;
  const int srow = l >> 2;
  const int skoff = (l & 3) * 8;

  for (int k0 = 0; k0 < KDIM; k0 += 32) {
#pragma unroll
    for (int i = 0; i < 2; ++i) {
      int chunk = i * 4 + w;
      int mrow = chunk * 16 + srow;
      gl_lds16(Ag + (size_t)mrow * KDIM + k0 + skoff, (char*)As + chunk * 1024);
      gl_lds16(Bg + (size_t)mrow * KDIM + k0 + skoff, (char*)Bs + chunk * 1024);
    }
    __syncthreads();

    bf16x8 a[4], b[4];
#pragma unroll
    for (int mi = 0; mi < 4; ++mi)
      a[mi] = *(const bf16x8*)((const char*)As +
                               (wr * 64 + mi * 16 + (l & 15)) * 64 + (l >> 4) * 16);
#pragma unroll
    for (int ni = 0; ni < 4; ++ni)
      b[ni] = *(const bf16x8*)((const char*)Bs +
                               (wc * 64 + ni * 16 + (l & 15)) * 64 + (l >> 4) * 16);
#pragma unroll
    for (int mi = 0; mi < 4; ++mi)
#pragma unroll
      for (int ni = 0; ni < 4; ++ni)
        acc[mi][ni] = __builtin_amdgcn_mfma_f32_16x16x32_bf16(a[mi], b[ni],
                                                              acc[mi][ni], 0, 0, 0);
    __syncthreads();
  }

#pragma unroll
  for (int mi = 0; mi < 4; ++mi) {
#pragma unroll
    for (int ni = 0; ni < 4; ++ni) {
      int row = r0 + wr * 64 + mi * 16 + (l >> 4) * 4;  // multiple of 4
      int col = c0 + wc * 64 + ni * 16 + (l & 15);
      float bv = bias[col];
      if (EPI == 0) {
#pragma unroll
        for (int j = 0; j < 4; ++j)
          fo[(size_t)(row + j) * D_DIM + col] = acc[mi][ni][j] + bv;
      } else {
        int which = col >> 10;  // 0=q,1=k,2=v
        int h = (col >> 6) & 15;
        int dh = col & 63;
        int b_ = row >> 11, t = row & 2047;  // uniform across j (row % 4 == 0)
        if (which == 2) {
          u16x4 pk;
#pragma unroll
          for (int j = 0; j < 4; ++j) pk[j] = f2bf(acc[mi][ni][j] + bv);
          *(u16x4*)(vto + ((size_t)(b_ * H_N + h) * DH_N + dh) * T_DIM + t) = pk;
        } else {
          float mul = (which == 0) ? 0.125f : 1.0f;
          unsigned short* dst = (which == 0) ? qo : ko;
#pragma unroll
          for (int j = 0; j < 4; ++j)
            dst[((size_t)(b_ * H_N + h) * T_DIM + t + j) * DH_N + dh] =
                f2bf((acc[mi][ni][j] + bv) * mul);
        }
      }
    }
  }
}

// ---------------------------------------------------------------------------
// MFMA windowed flash attention. Block = (b,h, 64 q-rows), 4 waves x 16 q.
// S^T = mfma(K,Q) with row-permuted K tile so P feeds PV's B-operand
// directly from registers (no shuffles, no LDS round-trip).
// ---------------------------------------------------------------------------
__global__ __launch_bounds__(256) void attn_mfma(
    const unsigned short* __restrict__ qbf,
    const unsigned short* __restrict__ kbf,
    const unsigned short* __restrict__ vtbf,
    unsigned short* __restrict__ ctx) {
  __shared__ unsigned short Ks[64 * 64];
  __shared__ unsigned short Vs[64 * 64];
  const int tid = threadIdx.x;
  const int w = tid >> 6, l = tid & 63;
  const int g = l >> 4, ln = l & 15;
  const int qt = blockIdx.x & 31;
  const int bh = blockIdx.x >> 5;
  const int q0 = qt * 64;
  const int q_abs = q0 + w * 16 + ln;

  const unsigned short* kp = kbf + (size_t)bh * T_DIM * DH_N;
  const unsigned short* vtp = vtbf + (size_t)bh * DH_N * T_DIM;

  bf16x8 qf0, qf1;
  {
    const unsigned short* qp = qbf + ((size_t)bh * T_DIM + q_abs) * DH_N;
    qf0 = *(const bf16x8*)(qp + g * 8);
    qf1 = *(const bf16x8*)(qp + 32 + g * 8);
  }

  f32x4 acc_o[4];
#pragma unroll
  for (int nd = 0; nd < 4; ++nd) acc_o[nd] = (f32x4){0.f, 0.f, 0.f, 0.f};
  float m = -1e30f, lsum = 0.f;

  const int kt_lo = (q0 >= WIN) ? (q0 - WIN) : 0;
  for (int kt = kt_lo; kt <= q0; kt += 64) {
    __syncthreads();  // previous tile reads done
#pragma unroll
    for (int i = 0; i < 2; ++i) {
      int chunk = i * 256 + tid;
      int row = chunk >> 3, c16 = chunk & 7;
      int sc16 = c16 ^ (row & 7);  // XOR swizzle (pre-applied on global src)
      // K row permutation kap(row): makes S^T lane layout == PV B-frag layout
      int kap = 32 * ((row >> 4) & 1) + 8 * ((row & 15) >> 2) + 4 * (row >> 5) +
                (row & 3);
      gl_lds16(kp + (size_t)(kt + kap) * DH_N + sc16 * 8, (char*)Ks + chunk * 16);
      gl_lds16(vtp + (size_t)row * T_DIM + kt + sc16 * 8, (char*)Vs + chunk * 16);
    }
    __syncthreads();  // staged data visible (vmcnt(0) before barrier)

    // S^T = K · Q^T   (A rows = permuted keys, B cols = q)
    f32x4 sacc[4];
#pragma unroll
    for (int nk = 0; nk < 4; ++nk) sacc[nk] = (f32x4){0.f, 0.f, 0.f, 0.f};
#pragma unroll
    for (int ks = 0; ks < 2; ++ks) {
      bf16x8 qf = ks ? qf1 : qf0;
#pragma unroll
      for (int nk = 0; nk < 4; ++nk) {
        int rrow = nk * 16 + ln;
        int c16 = ks * 4 + g;
        bf16x8 kf = *(const bf16x8*)((const char*)Ks + rrow * 128 +
                                     ((c16 ^ (rrow & 7)) * 16));
        sacc[nk] = __builtin_amdgcn_mfma_f32_16x16x32_bf16(kf, qf, sacc[nk], 0, 0, 0);
      }
    }

    // mask + online softmax (lane owns one q-row; keys spread over g)
    float p[4][4];
    float tm = -1e30f;
#pragma unroll
    for (int nk = 0; nk < 4; ++nk)
#pragma unroll
      for (int j = 0; j < 4; ++j) {
        // key for sacc[nk][j] = kt + kap(nk*16 + 4g + j)
        int k_abs = kt + 32 * (nk & 1) + 8 * g + 4 * (nk >> 1) + j;
        float s = sacc[nk][j];
        bool ok = (k_abs <= q_abs) && (k_abs + WIN >= q_abs);
        s = ok ? s : -1e30f;
        p[nk][j] = s;
        tm = fmaxf(tm, s);
      }
    tm = fmaxf(tm, __shfl_xor(tm, 16, 64));
    tm = fmaxf(tm, __shfl_xor(tm, 32, 64));
    float mn = fmaxf(m, tm);
    float sc = __expf(m - mn);
    float ps = 0.f;
#pragma unroll
    for (int nk = 0; nk < 4; ++nk)
#pragma unroll
      for (int j = 0; j < 4; ++j) {
        p[nk][j] = __expf(p[nk][j] - mn);
        ps += p[nk][j];
      }
    ps += __shfl_xor(ps, 16, 64);
    ps += __shfl_xor(ps, 32, 64);
    lsum = lsum * sc + ps;
    m = mn;
#pragma unroll
    for (int nd = 0; nd < 4; ++nd) {
      acc_o[nd][0] *= sc; acc_o[nd][1] *= sc;
      acc_o[nd][2] *= sc; acc_o[nd][3] *= sc;
    }

    // pack P to bf16 pairs (in-register; layout already matches B-frag)
    unsigned int pk[4][2];
#pragma unroll
    for (int nk = 0; nk < 4; ++nk) {
      pk[nk][0] = (unsigned)f2bf(p[nk][0]) | ((unsigned)f2bf(p[nk][1]) << 16);
      pk[nk][1] = (unsigned)f2bf(p[nk][2]) | ((unsigned)f2bf(p[nk][3]) << 16);
    }

    // O^T += V^T · P^T
#pragma unroll
    for (int ks = 0; ks < 2; ++ks) {
      union { unsigned int d[4]; bf16x8 v; } pf;
      pf.d[0] = pk[ks][0];     pf.d[1] = pk[ks][1];
      pf.d[2] = pk[2 + ks][0]; pf.d[3] = pk[2 + ks][1];
#pragma unroll
      for (int nd = 0; nd < 4; ++nd) {
        int drow = nd * 16 + ln;
        int c16 = ks * 4 + g;
        bf16x8 vf = *(const bf16x8*)((const char*)Vs + drow * 128 +
                                     ((c16 ^ (drow & 7)) * 16));
        acc_o[nd] = __builtin_amdgcn_mfma_f32_16x16x32_bf16(vf, pf.v, acc_o[nd],
                                                            0, 0, 0);
      }
    }
  }

  float inv = 1.f / lsum;
  const int b_ = bh >> 4, h = bh & 15;
  unsigned short* op = ctx + ((size_t)b_ * T_DIM + q_abs) * D_DIM + h * DH_N;
#pragma unroll
  for (int nd = 0; nd < 4; ++nd) {
    u16x4 o;
#pragma unroll
    for (int j = 0; j < 4; ++j) o[j] = f2bf(acc_o[nd][j] * inv);
    *(u16x4*)(op + nd * 16 + g * 4) = o;
  }
}

// ---------------------------------------------------------------------------
extern "C" void kernel_launch(void* const* d_in, const int* in_sizes, int n_in,
                              void* d_out, int out_size, void* d_ws,
                              size_t ws_size, hipStream_t stream) {
  const float* x = (const float*)d_in[0];
  const float* w_qkv = (const float*)d_in[1];
  const float* b_qkv = (const float*)d_in[2];
  const float* w_out = (const float*)d_in[3];
  const float* b_out = (const float*)d_in[4];
  float* out = (float*)d_out;

  const size_t per = (size_t)BN * H_N * T_DIM * DH_N;  // 4,194,304
  unsigned short* qbf = (unsigned short*)d_ws;
  unsigned short* kbf = qbf + per;
  unsigned short* vtbf = kbf + per;                    // [B,H,64,T]
  unsigned short* xbf = vtbf + per;                    // [4096][1024]
  unsigned short* wqkvt = xbf + (size_t)NROWS * D_DIM; // [3072][1024]
  unsigned short* woutt = wqkvt + (size_t)3 * D_DIM * D_DIM;  // [1024][1024]
  unsigned short* ctxbf = woutt + (size_t)D_DIM * D_DIM;      // [4096][1024]

  convert_bf<<<dim3(NROWS * D_DIM / (256 * 8)), dim3(256), 0, stream>>>(x, xbf);
  convert_t<<<dim3(3 * D_DIM / 64, D_DIM / 64), dim3(256), 0, stream>>>(
      w_qkv, wqkvt, D_DIM, 3 * D_DIM);
  convert_t<<<dim3(D_DIM / 64, D_DIM / 64), dim3(256), 0, stream>>>(
      w_out, woutt, D_DIM, D_DIM);

  mfma_gemm<1><<<dim3(3 * D_DIM / 128, NROWS / 128), dim3(256), 0, stream>>>(
      xbf, wqkvt, b_qkv, nullptr, qbf, kbf, vtbf);

  attn_mfma<<<dim3(BN * H_N * (T_DIM / 64)), dim3(256), 0, stream>>>(
      qbf, kbf, vtbf, ctxbf);

  mfma_gemm<0><<<dim3(D_DIM / 128, NROWS / 128), dim3(256), 0, stream>>>(
      ctxbf, woutt, b_out, out, nullptr, nullptr, nullptr);
}